// Round 11
// baseline (682.554 us; speedup 1.0000x reference)
//
#include <hip/hip_runtime.h>
#include <hip/hip_bf16.h>
#include <stdint.h>

#define B_  2
#define S_  4096
#define D_  1024
#define FF_ 4096
#define E_  8
#define C_  1024

typedef unsigned short u16;
typedef unsigned int   u32;
typedef float f32x4  __attribute__((ext_vector_type(4)));
typedef short bf16x8 __attribute__((ext_vector_type(8)));
typedef u16   u16x8  __attribute__((ext_vector_type(8)));

static __device__ __forceinline__ u16 f2bf(float f) {
    union { float f; u32 u; } v; v.f = f;
    u32 u = v.u;
    u32 r = (u + 0x7FFFu + ((u >> 16) & 1u)) >> 16;  // RNE; inputs are finite
    return (u16)r;
}

static __device__ __forceinline__ void gload_lds16(const u16* g, u16* l) {
    __builtin_amdgcn_global_load_lds(
        (const __attribute__((address_space(1))) u32*)g,
        (__attribute__((address_space(3))) u32*)l, 16, 0, 0);
}

#define BAR()    asm volatile("s_barrier" ::: "memory")
#define WAITV(n) asm volatile("s_waitcnt vmcnt(" #n ")" ::: "memory")
#define WAITL0() do { asm volatile("s_waitcnt lgkmcnt(0)" ::: "memory"); \
                      __builtin_amdgcn_sched_barrier(0); } while (0)

// ============ transpose + convert: [K][N] fp32 -> [N][K] bf16, per expert ============
__global__ __launch_bounds__(256) void transpose_cvt(const float* __restrict__ src,
                                                     u16* __restrict__ dst, int K, int N) {
    __shared__ u16 t[64 * 64];
    size_t mat = (size_t)blockIdx.z * K * N;
    int n0 = blockIdx.x * 64, k0 = blockIdx.y * 64;
    int l = threadIdx.x & 63, w = threadIdx.x >> 6;
#pragma unroll
    for (int p = 0; p < 2; ++p) {
        int k = p * 32 + w * 8 + ((l >> 4) << 1);     // even k
        int n = (l & 15) * 4;
        float4 v0 = *(const float4*)&src[mat + (size_t)(k0 + k) * N + n0 + n];
        float4 v1 = *(const float4*)&src[mat + (size_t)(k0 + k + 1) * N + n0 + n];
        float a0[4] = {v0.x, v0.y, v0.z, v0.w};
        float a1[4] = {v1.x, v1.y, v1.z, v1.w};
#pragma unroll
        for (int j = 0; j < 4; ++j) {
            int nn = n + j;
            u32 pk = (u32)f2bf(a0[j]) | ((u32)f2bf(a1[j]) << 16);
            int slot = (k >> 3) ^ ((nn & 7) ^ ((nn >> 3) & 7));
            *(u32*)((char*)t + nn * 128 + slot * 16 + (k & 7) * 2) = pk;
        }
    }
    __syncthreads();
#pragma unroll
    for (int p = 0; p < 2; ++p) {
        int n = p * 32 + (threadIdx.x >> 3);
        int k8 = threadIdx.x & 7;
        int slot = k8 ^ ((n & 7) ^ ((n >> 3) & 7));
        u16x8 v = *(u16x8*)((char*)t + n * 128 + slot * 16);
        *(u16x8*)&dst[mat + (size_t)(n0 + n) * K + k0 + k8 * 8] = v;
    }
}

// ============ router: logits (fp64 accum), argmax, max softmax prob ============
__global__ __launch_bounds__(256) void router_kernel(const float* __restrict__ hidden,
                                                     const float* __restrict__ gate_w,
                                                     float* __restrict__ logits_out,
                                                     int* __restrict__ sel,
                                                     float* __restrict__ maxp) {
    __shared__ float gw[D_ * E_];   // 32 KB
    for (int i = threadIdx.x; i < D_ * E_ / 4; i += 256)
        ((float4*)gw)[i] = ((const float4*)gate_w)[i];
    __syncthreads();

    int wave = threadIdx.x >> 6, lane = threadIdx.x & 63;
    int tok = blockIdx.x * 4 + wave;              // [0, B*S)
    const float* hrow = hidden + (size_t)tok * D_;

    double acc[8] = {0, 0, 0, 0, 0, 0, 0, 0};
#pragma unroll 4
    for (int i = 0; i < D_ / 64; i++) {
        int d = i * 64 + lane;
        float h = hrow[d];
        const float4* g4 = (const float4*)(gw + d * 8);
        float4 g0 = g4[0], g1 = g4[1];
        acc[0] += (double)h * g0.x; acc[1] += (double)h * g0.y;
        acc[2] += (double)h * g0.z; acc[3] += (double)h * g0.w;
        acc[4] += (double)h * g1.x; acc[5] += (double)h * g1.y;
        acc[6] += (double)h * g1.z; acc[7] += (double)h * g1.w;
    }
#pragma unroll
    for (int off = 32; off > 0; off >>= 1)
#pragma unroll
        for (int e = 0; e < 8; e++)
            acc[e] += __shfl_xor(acc[e], off);

    float l[8];
#pragma unroll
    for (int e = 0; e < 8; e++) l[e] = (float)acc[e];
    if (lane < 8) logits_out[(size_t)tok * 8 + lane] = l[lane];

    int am = 0; float mx = l[0];
#pragma unroll
    for (int e = 1; e < 8; e++) if (l[e] > mx) { mx = l[e]; am = e; }
    float sum = 0.f;
#pragma unroll
    for (int e = 0; e < 8; e++) sum += expf(l[e] - mx);
    if (lane == 0) { sel[tok] = am; maxp[tok] = 1.0f / sum; }
}

// ============ routing scan: hierarchical (histogram -> prefix -> assign), 1 block/batch ============
__global__ __launch_bounds__(1024) void scan_kernel(const int* __restrict__ sel,
                                                    int* __restrict__ pos,
                                                    int* __restrict__ slot_token,
                                                    int* __restrict__ counts,
                                                    int* __restrict__ ctr) {
    __shared__ int hist[16][8];
    __shared__ int base[16][8];
    int b = blockIdx.x;
    int tid = threadIdx.x, wv = tid >> 6, l = tid & 63;
    if (b == 0 && tid == 0) ctr[0] = 0;     // reset work-stealing counter each launch
    unsigned long long below = (l == 0) ? 0ull : ((~0ull) >> (64 - l));
    const int* sb = sel + b * S_;

    int eloc[4];
    int cnt[8] = {0, 0, 0, 0, 0, 0, 0, 0};
#pragma unroll
    for (int c = 0; c < 4; c++) {
        int s = wv * 256 + c * 64 + l;
        int e = sb[s];
        eloc[c] = e;
#pragma unroll
        for (int ex = 0; ex < 8; ex++)
            cnt[ex] += (int)__popcll(__ballot(e == ex));
    }
    if (l == 0)
#pragma unroll
        for (int ex = 0; ex < 8; ex++) hist[wv][ex] = cnt[ex];
    __syncthreads();
    if (tid < 128) {
        int ex = tid & 7, v = tid >> 3;
        int s = 0;
        for (int w2 = 0; w2 < v; w2++) s += hist[w2][ex];
        base[v][ex] = s;
        if (v == 15) {
            int tot = s + hist[15][ex];
            counts[b * 8 + ex] = tot < C_ ? tot : C_;
        }
    }
    __syncthreads();
    int carry[8];
#pragma unroll
    for (int ex = 0; ex < 8; ex++) carry[ex] = base[wv][ex];
#pragma unroll
    for (int c = 0; c < 4; c++) {
        int s = wv * 256 + c * 64 + l;
        int e = eloc[c];
        int p = 0;
#pragma unroll
        for (int ex = 0; ex < 8; ex++) {
            unsigned long long m = __ballot(e == ex);
            if (e == ex) p = carry[ex] + (int)__popcll(m & below);
            carry[ex] += (int)__popcll(m);
        }
        pos[b * S_ + s] = p;
        if (p < C_) slot_token[(b * E_ + e) * C_ + p] = s;
    }
}

// ============ gather: xg[z][slot][:] = bf16(hidden[token(slot)][:]) — coalesced both sides ============
__global__ __launch_bounds__(256) void gather_kernel(const float* __restrict__ hidden,
                                                     const int* __restrict__ slot_token,
                                                     const int* __restrict__ counts,
                                                     u16* __restrict__ xg) {
    int z = blockIdx.x >> 8;                    // 256 blocks per z, 4 rows per block
    int r0 = (blockIdx.x & 255) * 4;
    int cnt = counts[z];
    int slot = r0 + (threadIdx.x >> 6);
    if (slot >= cnt) return;
    int l = threadIdx.x & 63;
    int b = z >> 3;
    int tok = slot_token[z * C_ + slot];
    const float4* src = (const float4*)(hidden + (size_t)(b * S_ + tok) * D_) + l * 4;
    u16x8* dst = (u16x8*)(xg + ((size_t)z * C_ + slot) * D_) + l * 2;
#pragma unroll
    for (int h = 0; h < 2; h++) {
        float4 a = src[h * 2], c = src[h * 2 + 1];
        u16x8 o;
        o[0] = f2bf(a.x); o[1] = f2bf(a.y); o[2] = f2bf(a.z); o[3] = f2bf(a.w);
        o[4] = f2bf(c.x); o[5] = f2bf(c.y); o[6] = f2bf(c.z); o[7] = f2bf(c.w);
        dst[h] = o;
    }
}

// ============ GEMM1: h = silu(x@w1) * (x@w3) — persistent work-stealing ============
// 512 persistent blocks (2/CU), 256 threads (4 waves of 128x64). Item = 128(slots) x
// 256(B rows: w1/w3 interleaved by 32 over 128 ff), decoded i = ((z*32+ffx)*8+cy) so
// consecutive items share the (z,ffx) weight panel. Inner body identical to R10:
// BK=32, 3-slot LDS rotation (72 KB), counted prefetch depth 2 (WAITV(6)),
// R4-verified 0-conflict chunk-XOR layout.
#define G1_NITEMS (16 * 32 * 8)
__global__ __launch_bounds__(256, 2) void gemm1_kernel(const u16* __restrict__ xg,
                                                       const u16* __restrict__ w1t,
                                                       const u16* __restrict__ w3t,
                                                       const int* __restrict__ counts,
                                                       u16* __restrict__ hbuf,
                                                       int* __restrict__ ctr) {
    extern __shared__ u16 lds[];   // 3 * 12288 u16 = 72 KB  (slot: A 128x32 | B 256x32)
    __shared__ int s_item;

    int tid = threadIdx.x, wn = tid >> 6, l = tid & 63;
    u32 ck = (u32)(((l >> 4) ^ ((l >> 1) & 3)) * 8);
    u32 dA = (u32)tid * 8;           // + i*2048 within slot
    u32 dB = 4096 + (u32)tid * 8;    // + i*2048
    int srcxor = ((tid & 3) ^ ((tid >> 3) & 3)) * 8;   // inverse chunk swizzle k-offset

    for (;;) {
        if (tid == 0) s_item = atomicAdd(ctr, 1);
        __syncthreads();             // publish s_item; also fences LDS reuse across items
        int item = s_item;
        if (item >= G1_NITEMS) break;
        int cy = item & 7, ffx = (item >> 3) & 31, z = item >> 8;
        int cnt = counts[z];
        int c0 = cy * 128;
        if (c0 >= cnt) continue;
        int n0 = ffx * 128;
        int e = z & 7;

        // staging sources (contiguous rows; source k-chunk inverse-swizzled)
        const u16* pA[2];
#pragma unroll
        for (int i = 0; i < 2; i++) {
            int q = i * 256 + tid;
            int r = q >> 2;
            pA[i] = xg + ((size_t)z * C_ + c0 + r) * D_ + srcxor;
        }
        const u16* pB[4];
#pragma unroll
        for (int i = 0; i < 4; i++) {
            int q = i * 256 + tid;
            int R = q >> 2;
            int panel = (R >> 5) & 1;
            int ffl = ((R >> 6) << 5) + (R & 31);
            const u16* wmat = panel ? w3t : w1t;
            pB[i] = wmat + ((size_t)e * FF_ + n0 + ffl) * D_ + srcxor;
        }

        f32x4 acc[8][4] = {};

        auto STAGE = [&](int t) {
            u16* Ls = lds + (t % 3) * 12288;
            int ko = t << 5;
#pragma unroll
            for (int i = 0; i < 2; i++) gload_lds16(pA[i] + ko, Ls + dA + i * 2048);
#pragma unroll
            for (int i = 0; i < 4; i++) gload_lds16(pB[i] + ko, Ls + dB + i * 2048);
        };

        constexpr int NK = D_ / 32;  // 32
        STAGE(0); STAGE(1);
        for (int t = 0; t < NK; ++t) {
            if (t + 1 < NK) { WAITV(6); } else { WAITV(0); }
            BAR();
            const u16* Ls = lds + (t % 3) * 12288;
            bf16x8 af[8], bf[4];
#pragma unroll
            for (int f = 0; f < 8; f++)
                af[f] = *(const bf16x8*)(Ls + (u32)(f * 16 + (l & 15)) * 32 + ck);
#pragma unroll
            for (int j = 0; j < 4; j++)
                bf[j] = *(const bf16x8*)(Ls + 4096 + (u32)(wn * 64 + j * 16 + (l & 15)) * 32 + ck);
            if (t + 2 < NK) STAGE(t + 2);
            WAITL0();
            __builtin_amdgcn_s_setprio(1);
#pragma unroll
            for (int f = 0; f < 8; f++)
#pragma unroll
                for (int j = 0; j < 4; j++)
                    acc[f][j] = __builtin_amdgcn_mfma_f32_16x16x32_bf16(af[f], bf[j], acc[f][j], 0, 0, 0);
            __builtin_amdgcn_s_setprio(0);
        }

#pragma unroll
        for (int f = 0; f < 8; f++) {
            int rb = c0 + f * 16 + ((l >> 4) << 2);
#pragma unroll
            for (int j = 0; j < 2; j++) {
                int ff = n0 + wn * 32 + j * 16 + (l & 15);
#pragma unroll
                for (int r = 0; r < 4; r++) {
                    int slot = rb + r;
                    if (slot < cnt) {
                        float g = acc[f][j][r], uu = acc[f][j + 2][r];
                        float h = (g / (1.f + __expf(-g))) * uu;
                        hbuf[((size_t)z * C_ + slot) * FF_ + ff] = f2bf(h);
                    }
                }
            }
        }
    }
}

// ============ GEMM2: out[token] = maxp * (h @ w2), scatter epilogue ============
// (unchanged control) tile 256(M) x 256(N). K-step=32, 4-slot rotation, depth 3,
// 8 waves (2M x 4N), 2-sub-phase schedule.
__global__ __launch_bounds__(512, 2) void gemm2_kernel(const u16* __restrict__ hbuf,
                                                       const u16* __restrict__ w2t,
                                                       const int* __restrict__ slot_token,
                                                       const int* __restrict__ counts,
                                                       const float* __restrict__ maxp,
                                                       float* __restrict__ out) {
    extern __shared__ u16 lds[];   // 128 KB
    // bijective XCD chunk swizzle (nwg = 256, q = 32)
    int phys = blockIdx.x + 4 * (blockIdx.y + 4 * blockIdx.z);
    int virt = (phys & 7) * 32 + (phys >> 3);
    int bx = virt & 3, by = (virt >> 2) & 3, bz = virt >> 4;

    int z = bz;
    int cnt = counts[z];
    int c0 = by * 256;
    if (c0 >= cnt) return;
    int n0 = bx * 256;
    int b = z >> 3, e = z & 7;

    int tid = threadIdx.x, w = tid >> 6, l = tid & 63;
    int wm = w >> 2, wn = w & 3;

    int arow0 = tid >> 2;
    int lk = ((tid & 3) ^ ((tid >> 3) & 3)) * 8;
    const u16* pA0 = hbuf + ((size_t)z * C_ + c0 + arow0) * FF_ + lk;
    const u16* pA1 = pA0 + (size_t)128 * FF_;
    const u16* pB0 = w2t + ((size_t)e * D_ + n0 + arow0) * FF_ + lk;
    const u16* pB1 = pB0 + (size_t)128 * FF_;
    u32 wsl = (u32)tid * 8;

    u32 ck  = (u32)(((l >> 4) ^ ((l >> 1) & 3)) * 8);
    u32 aoff = (u32)(wm * 128 + (l & 15)) * 32 + ck;                 // + f*512
    u32 boff = 8192 + (u32)(wn * 64 + (l & 15)) * 32 + ck;           // + n*512

    auto STAGE_A = [&](int t) {
        u16* Ls = lds + ((t & 3) << 14);
        int ko = t << 5;
        gload_lds16(pA0 + ko, Ls + wsl);
        gload_lds16(pA1 + ko, Ls + 4096 + wsl);
    };
    auto STAGE_B = [&](int t) {
        u16* Ls = lds + ((t & 3) << 14);
        int ko = t << 5;
        gload_lds16(pB0 + ko, Ls + 8192 + wsl);
        gload_lds16(pB1 + ko, Ls + 12288 + wsl);
    };

    f32x4 acc[8][4] = {};

    constexpr int NK = FF_ / 32;  // 128
    STAGE_A(0); STAGE_B(0); STAGE_A(1); STAGE_B(1); STAGE_A(2); STAGE_B(2);
    for (int t = 0; t < NK; ++t) {
        if (t + 2 < NK)      { WAITV(8); }
        else if (t + 1 < NK) { WAITV(4); }
        else                 { WAITV(0); }
        BAR();
        const u16* Ls = lds + ((t & 3) << 14);
        bf16x8 af[8], bfv[4];
#pragma unroll
        for (int f = 0; f < 4; f++) af[f] = *(const bf16x8*)(Ls + aoff + f * 512);
#pragma unroll
        for (int n = 0; n < 4; n++) bfv[n] = *(const bf16x8*)(Ls + boff + n * 512);
        if (t + 3 < NK) STAGE_A(t + 3);
        WAITL0();
        __builtin_amdgcn_s_setprio(1);
#pragma unroll
        for (int f = 0; f < 4; f++)
#pragma unroll
            for (int n = 0; n < 4; n++)
                acc[f][n] = __builtin_amdgcn_mfma_f32_16x16x32_bf16(af[f], bfv[n], acc[f][n], 0, 0, 0);
        __builtin_amdgcn_s_setprio(0);
        BAR();
#pragma unroll
        for (int f = 4; f < 8; f++) af[f] = *(const bf16x8*)(Ls + aoff + f * 512);
        if (t + 3 < NK) STAGE_B(t + 3);
        WAITL0();
        __builtin_amdgcn_s_setprio(1);
#pragma unroll
        for (int f = 4; f < 8; f++)
#pragma unroll
            for (int n = 0; n < 4; n++)
                acc[f][n] = __builtin_amdgcn_mfma_f32_16x16x32_bf16(af[f], bfv[n], acc[f][n], 0, 0, 0);
        __builtin_amdgcn_s_setprio(0);
    }

#pragma unroll
    for (int f = 0; f < 8; f++) {
        int row = wm * 128 + f * 16 + ((l >> 4) << 2);
#pragma unroll
        for (int rr = 0; rr < 4; rr++) {
            int slot = c0 + row + rr;
            if (slot < cnt) {
                int s = slot_token[z * C_ + slot];
                float sc = maxp[b * S_ + s];
                float* orow = out + ((size_t)b * S_ + s) * D_ + n0 + wn * 64 + (l & 15);
#pragma unroll
                for (int n = 0; n < 4; n++)
                    orow[n * 16] = sc * acc[f][n][rr];
            }
        }
    }
}

// ============ dropped tokens keep hidden (rare; usually no-op) ============
__global__ __launch_bounds__(256) void combine_dropped(const float* __restrict__ hidden,
                                                       const int* __restrict__ pos,
                                                       const float* __restrict__ maxp,
                                                       float* __restrict__ out) {
    int t = blockIdx.x;
    if (pos[t] < C_) return;
    float sc = maxp[t];
    const float* src = hidden + (size_t)t * D_;
    float* dst = out + (size_t)t * D_;
    for (int d = threadIdx.x; d < D_; d += 256) dst[d] = sc * src[d];
}

extern "C" void kernel_launch(void* const* d_in, const int* in_sizes, int n_in,
                              void* d_out, int out_size, void* d_ws, size_t ws_size,
                              hipStream_t stream) {
    const float* hidden = (const float*)d_in[0];
    const float* gate_w = (const float*)d_in[1];
    const float* w1     = (const float*)d_in[2];
    const float* w2     = (const float*)d_in[3];
    const float* w3     = (const float*)d_in[4];

    float* out        = (float*)d_out;
    float* logits_out = out + (size_t)B_ * S_ * D_;

    char* ws = (char*)d_ws;
    u16* xg        = (u16*)ws;            ws += (size_t)B_ * E_ * C_ * D_ * 2;   // 32 MB
    u16* w1t       = (u16*)ws;            ws += (size_t)E_ * D_ * FF_ * 2;
    u16* w3t       = (u16*)ws;            ws += (size_t)E_ * D_ * FF_ * 2;
    u16* w2t       = (u16*)ws;            ws += (size_t)E_ * D_ * FF_ * 2;
    u16* hbuf      = (u16*)ws;            ws += (size_t)B_ * E_ * C_ * FF_ * 2;
    int*   sel        = (int*)ws;         ws += (size_t)B_ * S_ * 4;
    int*   pos        = (int*)ws;         ws += (size_t)B_ * S_ * 4;
    float* maxp       = (float*)ws;       ws += (size_t)B_ * S_ * 4;
    int*   slot_token = (int*)ws;         ws += (size_t)B_ * E_ * C_ * 4;
    int*   counts     = (int*)ws;         ws += (size_t)B_ * E_ * 4;
    int*   ctr        = (int*)ws;         ws += 256;

    (void)hipFuncSetAttribute((const void*)gemm1_kernel,
                              hipFuncAttributeMaxDynamicSharedMemorySize, 73728);
    (void)hipFuncSetAttribute((const void*)gemm2_kernel,
                              hipFuncAttributeMaxDynamicSharedMemorySize, 131072);

    router_kernel<<<B_ * S_ / 4, 256, 0, stream>>>(hidden, gate_w, logits_out, sel, maxp);
    scan_kernel<<<B_, 1024, 0, stream>>>(sel, pos, slot_token, counts, ctr);
    gather_kernel<<<B_ * E_ * 256, 256, 0, stream>>>(hidden, slot_token, counts, xg);

    transpose_cvt<<<dim3(FF_ / 64, D_ / 64, E_), 256, 0, stream>>>(w1, w1t, D_, FF_);
    transpose_cvt<<<dim3(FF_ / 64, D_ / 64, E_), 256, 0, stream>>>(w3, w3t, D_, FF_);
    transpose_cvt<<<dim3(D_ / 64, FF_ / 64, E_), 256, 0, stream>>>(w2, w2t, FF_, D_);

    gemm1_kernel<<<512, 256, 73728, stream>>>(xg, w1t, w3t, counts, hbuf, ctr);
    gemm2_kernel<<<dim3(4, 4, 16), 512, 131072, stream>>>(hbuf, w2t, slot_token, counts, maxp, out);
    combine_dropped<<<B_ * S_, 256, 0, stream>>>(hidden, pos, maxp, out);
}

// Round 13
// 515.204 us; speedup vs baseline: 1.3248x; 1.3248x over previous
//
#include <hip/hip_runtime.h>
#include <hip/hip_bf16.h>
#include <stdint.h>

#define B_  2
#define S_  4096
#define D_  1024
#define FF_ 4096
#define E_  8
#define C_  1024

typedef unsigned short u16;
typedef unsigned int   u32;
typedef float f32x4  __attribute__((ext_vector_type(4)));
typedef short bf16x8 __attribute__((ext_vector_type(8)));
typedef u16   u16x8  __attribute__((ext_vector_type(8)));

static __device__ __forceinline__ u16 f2bf(float f) {
    union { float f; u32 u; } v; v.f = f;
    u32 u = v.u;
    u32 r = (u + 0x7FFFu + ((u >> 16) & 1u)) >> 16;  // RNE; inputs are finite
    return (u16)r;
}

static __device__ __forceinline__ void gload_lds16(const u16* g, u16* l) {
    __builtin_amdgcn_global_load_lds(
        (const __attribute__((address_space(1))) u32*)g,
        (__attribute__((address_space(3))) u32*)l, 16, 0, 0);
}

#define BAR()    asm volatile("s_barrier" ::: "memory")
#define WAITV(n) asm volatile("s_waitcnt vmcnt(" #n ")" ::: "memory")
#define WAITL0() do { asm volatile("s_waitcnt lgkmcnt(0)" ::: "memory"); \
                      __builtin_amdgcn_sched_barrier(0); } while (0)

// ============ transpose + convert: [K][N] fp32 -> [N][K] bf16, per expert ============
__global__ __launch_bounds__(256) void transpose_cvt(const float* __restrict__ src,
                                                     u16* __restrict__ dst, int K, int N) {
    __shared__ u16 t[64 * 64];
    size_t mat = (size_t)blockIdx.z * K * N;
    int n0 = blockIdx.x * 64, k0 = blockIdx.y * 64;
    int l = threadIdx.x & 63, w = threadIdx.x >> 6;
#pragma unroll
    for (int p = 0; p < 2; ++p) {
        int k = p * 32 + w * 8 + ((l >> 4) << 1);     // even k
        int n = (l & 15) * 4;
        float4 v0 = *(const float4*)&src[mat + (size_t)(k0 + k) * N + n0 + n];
        float4 v1 = *(const float4*)&src[mat + (size_t)(k0 + k + 1) * N + n0 + n];
        float a0[4] = {v0.x, v0.y, v0.z, v0.w};
        float a1[4] = {v1.x, v1.y, v1.z, v1.w};
#pragma unroll
        for (int j = 0; j < 4; ++j) {
            int nn = n + j;
            u32 pk = (u32)f2bf(a0[j]) | ((u32)f2bf(a1[j]) << 16);
            int slot = (k >> 3) ^ ((nn & 7) ^ ((nn >> 3) & 7));
            *(u32*)((char*)t + nn * 128 + slot * 16 + (k & 7) * 2) = pk;
        }
    }
    __syncthreads();
#pragma unroll
    for (int p = 0; p < 2; ++p) {
        int n = p * 32 + (threadIdx.x >> 3);
        int k8 = threadIdx.x & 7;
        int slot = k8 ^ ((n & 7) ^ ((n >> 3) & 7));
        u16x8 v = *(u16x8*)((char*)t + n * 128 + slot * 16);
        *(u16x8*)&dst[mat + (size_t)(n0 + n) * K + k0 + k8 * 8] = v;
    }
}

// ============ router: logits (fp64 accum), argmax, max softmax prob ============
__global__ __launch_bounds__(256) void router_kernel(const float* __restrict__ hidden,
                                                     const float* __restrict__ gate_w,
                                                     float* __restrict__ logits_out,
                                                     int* __restrict__ sel,
                                                     float* __restrict__ maxp) {
    __shared__ float gw[D_ * E_];   // 32 KB
    for (int i = threadIdx.x; i < D_ * E_ / 4; i += 256)
        ((float4*)gw)[i] = ((const float4*)gate_w)[i];
    __syncthreads();

    int wave = threadIdx.x >> 6, lane = threadIdx.x & 63;
    int tok = blockIdx.x * 4 + wave;              // [0, B*S)
    const float* hrow = hidden + (size_t)tok * D_;

    double acc[8] = {0, 0, 0, 0, 0, 0, 0, 0};
#pragma unroll 4
    for (int i = 0; i < D_ / 64; i++) {
        int d = i * 64 + lane;
        float h = hrow[d];
        const float4* g4 = (const float4*)(gw + d * 8);
        float4 g0 = g4[0], g1 = g4[1];
        acc[0] += (double)h * g0.x; acc[1] += (double)h * g0.y;
        acc[2] += (double)h * g0.z; acc[3] += (double)h * g0.w;
        acc[4] += (double)h * g1.x; acc[5] += (double)h * g1.y;
        acc[6] += (double)h * g1.z; acc[7] += (double)h * g1.w;
    }
#pragma unroll
    for (int off = 32; off > 0; off >>= 1)
#pragma unroll
        for (int e = 0; e < 8; e++)
            acc[e] += __shfl_xor(acc[e], off);

    float l[8];
#pragma unroll
    for (int e = 0; e < 8; e++) l[e] = (float)acc[e];
    if (lane < 8) logits_out[(size_t)tok * 8 + lane] = l[lane];

    int am = 0; float mx = l[0];
#pragma unroll
    for (int e = 1; e < 8; e++) if (l[e] > mx) { mx = l[e]; am = e; }
    float sum = 0.f;
#pragma unroll
    for (int e = 0; e < 8; e++) sum += expf(l[e] - mx);
    if (lane == 0) { sel[tok] = am; maxp[tok] = 1.0f / sum; }
}

// ============ routing scan: hierarchical (histogram -> prefix -> assign), 1 block/batch ============
__global__ __launch_bounds__(1024) void scan_kernel(const int* __restrict__ sel,
                                                    int* __restrict__ pos,
                                                    int* __restrict__ slot_token,
                                                    int* __restrict__ counts) {
    __shared__ int hist[16][8];
    __shared__ int base[16][8];
    int b = blockIdx.x;
    int tid = threadIdx.x, wv = tid >> 6, l = tid & 63;
    unsigned long long below = (l == 0) ? 0ull : ((~0ull) >> (64 - l));
    const int* sb = sel + b * S_;

    int eloc[4];
    int cnt[8] = {0, 0, 0, 0, 0, 0, 0, 0};
#pragma unroll
    for (int c = 0; c < 4; c++) {
        int s = wv * 256 + c * 64 + l;
        int e = sb[s];
        eloc[c] = e;
#pragma unroll
        for (int ex = 0; ex < 8; ex++)
            cnt[ex] += (int)__popcll(__ballot(e == ex));
    }
    if (l == 0)
#pragma unroll
        for (int ex = 0; ex < 8; ex++) hist[wv][ex] = cnt[ex];
    __syncthreads();
    if (tid < 128) {
        int ex = tid & 7, v = tid >> 3;
        int s = 0;
        for (int w2 = 0; w2 < v; w2++) s += hist[w2][ex];
        base[v][ex] = s;
        if (v == 15) {
            int tot = s + hist[15][ex];
            counts[b * 8 + ex] = tot < C_ ? tot : C_;
        }
    }
    __syncthreads();
    int carry[8];
#pragma unroll
    for (int ex = 0; ex < 8; ex++) carry[ex] = base[wv][ex];
#pragma unroll
    for (int c = 0; c < 4; c++) {
        int s = wv * 256 + c * 64 + l;
        int e = eloc[c];
        int p = 0;
#pragma unroll
        for (int ex = 0; ex < 8; ex++) {
            unsigned long long m = __ballot(e == ex);
            if (e == ex) p = carry[ex] + (int)__popcll(m & below);
            carry[ex] += (int)__popcll(m);
        }
        pos[b * S_ + s] = p;
        if (p < C_) slot_token[(b * E_ + e) * C_ + p] = s;
    }
}

// ============ gather: xg[z][slot][:] = bf16(hidden[token(slot)][:]) — coalesced both sides ============
__global__ __launch_bounds__(256) void gather_kernel(const float* __restrict__ hidden,
                                                     const int* __restrict__ slot_token,
                                                     const int* __restrict__ counts,
                                                     u16* __restrict__ xg) {
    int z = blockIdx.x >> 8;                    // 256 blocks per z, 4 rows per block
    int r0 = (blockIdx.x & 255) * 4;
    int cnt = counts[z];
    int slot = r0 + (threadIdx.x >> 6);
    if (slot >= cnt) return;
    int l = threadIdx.x & 63;
    int b = z >> 3;
    int tok = slot_token[z * C_ + slot];
    const float4* src = (const float4*)(hidden + (size_t)(b * S_ + tok) * D_) + l * 4;
    u16x8* dst = (u16x8*)(xg + ((size_t)z * C_ + slot) * D_) + l * 2;
#pragma unroll
    for (int h = 0; h < 2; h++) {
        float4 a = src[h * 2], c = src[h * 2 + 1];
        u16x8 o;
        o[0] = f2bf(a.x); o[1] = f2bf(a.y); o[2] = f2bf(a.z); o[3] = f2bf(a.w);
        o[4] = f2bf(c.x); o[5] = f2bf(c.y); o[6] = f2bf(c.z); o[7] = f2bf(c.w);
        dst[h] = o;
    }
}

// ============ GEMM1: h = silu(x@w1) * (x@w3) — m201 8-phase port (grid-coverage fixed) ============
// BM=256(slots) x BN=256(B rows: w1/w3 interleaved by 32 over 128 ff), BK=64, 512 thr
// (8 waves 2Mx4N, wave 128x64). LDS 128 KB = 2 dbuf x {A: 2half x [2kk][128][32],
// B: same}. 64B-row chunk-XOR layout (R4-verified 0 conflicts). 4 phases per K-tile:
// {ds_reads || 2 gload_lds(T+1 half-group) -> lgkm0 -> setprio 16 MFMA}, counted
// WAITV(4) only at phases 0,2 (ledger: 8 outstanding max, never drains mid-loop).
// FIX vs R12: cy in 0..3 (c0 covers all C=1024 slots); grid 2048.
__global__ __launch_bounds__(512, 1) void gemm1_kernel(const u16* __restrict__ xg,
                                                       const u16* __restrict__ w1t,
                                                       const u16* __restrict__ w3t,
                                                       const int* __restrict__ counts,
                                                       u16* __restrict__ hbuf) {
    extern __shared__ u16 lds[];   // 65536 u16 = 128 KB
    // bijective XCD swizzle, nwg = 2048, q = 256; c inner, then ffx, then z
    int phys = blockIdx.x;
    int virt = (phys & 7) * 256 + (phys >> 3);
    int cy = virt & 3, ffx = (virt >> 2) & 31, z = virt >> 7;

    int cnt = counts[z];
    int c0 = cy * 256;
    if (c0 >= cnt) return;
    int n0 = ffx * 128;
    int e = z & 7;

    int tid = threadIdx.x, w = tid >> 6, l = tid & 63;
    int wm = w >> 2, wn = w & 3;

    // ---- staging sources: thread covers (r = tid>>2, c = tid&3) ----
    int r = tid >> 2;
    int lc = ((tid & 3) ^ ((tid >> 3) & 3)) * 8;   // inverse chunk swizzle k-offset
    const u16* pA[2];   // h = 0,1 (row half)
#pragma unroll
    for (int h = 0; h < 2; h++)
        pA[h] = xg + ((size_t)z * C_ + c0 + h * 128 + r) * D_ + lc;
    const u16* pB[2];
#pragma unroll
    for (int h = 0; h < 2; h++) {
        int R = h * 128 + r;                        // 0..255 B-row
        int panel = (R >> 5) & 1;
        int ffl = ((R >> 6) << 5) + (R & 31);
        const u16* wmat = panel ? w3t : w1t;
        pB[h] = wmat + ((size_t)e * FF_ + n0 + ffl) * D_ + lc;
    }
    u32 dstA = (u32)tid * 8;            // + buf*32768 + h*8192 + kk*4096
    u32 dstB = 16384 + (u32)tid * 8;

    // ---- fragment read offsets ----
    u32 ck = (u32)(((l >> 4) ^ ((l >> 1) & 3)) * 8);
    u32 aBase = (u32)wm * 8192 + (u32)(l & 15) * 32 + ck;
    u32 bBase = 16384 + (u32)(wn >> 1) * 8192 + (u32)((wn & 1) * 64 + (l & 15)) * 32 + ck;

    f32x4 acc[8][4] = {};
    bf16x8 bfr[4];

    // stage one half-group: grp 0=A@kk0, 1=B@kk0, 2=A@kk1, 3=B@kk1 (2 instrs each)
    auto STAGE = [&](int T, int grp) {
        u32 buf = ((u32)T & 1) * 32768;
        int kk = grp >> 1;
        int ko = (T << 6) + (kk << 5);
        if ((grp & 1) == 0) {
#pragma unroll
            for (int h = 0; h < 2; h++)
                gload_lds16(pA[h] + ko, lds + buf + (u32)h * 8192 + (u32)kk * 4096 + dstA);
        } else {
#pragma unroll
            for (int h = 0; h < 2; h++)
                gload_lds16(pB[h] + ko, lds + buf + (u32)h * 8192 + (u32)kk * 4096 + dstB);
        }
    };

    constexpr int NT = D_ / 64;  // 16
    STAGE(0, 0); STAGE(0, 1); STAGE(0, 2); STAGE(0, 3);

    for (int T = 0; T < NT; ++T) {
        u32 buf = ((u32)T & 1) * 32768;
        bool st = (T + 1 < NT);
#pragma unroll
        for (int ph = 0; ph < 4; ph++) {
            int kk = ph >> 1, fh = ph & 1;
            if (ph == 0) { WAITV(4); }
            else if (ph == 2) { if (st) { WAITV(4); } else { WAITV(0); } }
            BAR();
            const u16* Lk = lds + buf + (u32)kk * 4096;
            bf16x8 af[4];
#pragma unroll
            for (int f = 0; f < 4; f++)
                af[f] = *(const bf16x8*)(Lk + aBase + (u32)(fh * 4 + f) * 512);
            if (fh == 0) {
#pragma unroll
                for (int j = 0; j < 4; j++)
                    bfr[j] = *(const bf16x8*)(Lk + bBase + (u32)j * 512);
            }
            if (st) STAGE(T + 1, ph);
            WAITL0();
            __builtin_amdgcn_s_setprio(1);
#pragma unroll
            for (int f = 0; f < 4; f++)
#pragma unroll
                for (int j = 0; j < 4; j++)
                    acc[fh * 4 + f][j] = __builtin_amdgcn_mfma_f32_16x16x32_bf16(
                        af[f], bfr[j], acc[fh * 4 + f][j], 0, 0, 0);
            __builtin_amdgcn_s_setprio(0);
            BAR();
        }
    }

    // epilogue: acc[f][j] j<2 = w1 (gate), j>=2 = w3 (up)
#pragma unroll
    for (int f = 0; f < 8; f++) {
        int rb = c0 + wm * 128 + f * 16 + ((l >> 4) << 2);
#pragma unroll
        for (int j = 0; j < 2; j++) {
            int ff = n0 + wn * 32 + j * 16 + (l & 15);
#pragma unroll
            for (int rr = 0; rr < 4; rr++) {
                int slot = rb + rr;
                if (slot < cnt) {
                    float g = acc[f][j][rr], uu = acc[f][j + 2][rr];
                    float h = (g / (1.f + __expf(-g))) * uu;
                    hbuf[((size_t)z * C_ + slot) * FF_ + ff] = f2bf(h);
                }
            }
        }
    }
}

// ============ GEMM2: out[token] = maxp * (h @ w2), scatter epilogue ============
// (unchanged control) tile 256(M) x 256(N). K-step=32, 4-slot rotation, depth 3,
// 8 waves (2M x 4N), 2-sub-phase schedule.
__global__ __launch_bounds__(512, 2) void gemm2_kernel(const u16* __restrict__ hbuf,
                                                       const u16* __restrict__ w2t,
                                                       const int* __restrict__ slot_token,
                                                       const int* __restrict__ counts,
                                                       const float* __restrict__ maxp,
                                                       float* __restrict__ out) {
    extern __shared__ u16 lds[];   // 128 KB
    // bijective XCD chunk swizzle (nwg = 256, q = 32)
    int phys = blockIdx.x + 4 * (blockIdx.y + 4 * blockIdx.z);
    int virt = (phys & 7) * 32 + (phys >> 3);
    int bx = virt & 3, by = (virt >> 2) & 3, bz = virt >> 4;

    int z = bz;
    int cnt = counts[z];
    int c0 = by * 256;
    if (c0 >= cnt) return;
    int n0 = bx * 256;
    int b = z >> 3, e = z & 7;

    int tid = threadIdx.x, w = tid >> 6, l = tid & 63;
    int wm = w >> 2, wn = w & 3;

    int arow0 = tid >> 2;
    int lk = ((tid & 3) ^ ((tid >> 3) & 3)) * 8;
    const u16* pA0 = hbuf + ((size_t)z * C_ + c0 + arow0) * FF_ + lk;
    const u16* pA1 = pA0 + (size_t)128 * FF_;
    const u16* pB0 = w2t + ((size_t)e * D_ + n0 + arow0) * FF_ + lk;
    const u16* pB1 = pB0 + (size_t)128 * FF_;
    u32 wsl = (u32)tid * 8;

    u32 ck  = (u32)(((l >> 4) ^ ((l >> 1) & 3)) * 8);
    u32 aoff = (u32)(wm * 128 + (l & 15)) * 32 + ck;                 // + f*512
    u32 boff = 8192 + (u32)(wn * 64 + (l & 15)) * 32 + ck;           // + n*512

    auto STAGE_A = [&](int t) {
        u16* Ls = lds + ((t & 3) << 14);
        int ko = t << 5;
        gload_lds16(pA0 + ko, Ls + wsl);
        gload_lds16(pA1 + ko, Ls + 4096 + wsl);
    };
    auto STAGE_B = [&](int t) {
        u16* Ls = lds + ((t & 3) << 14);
        int ko = t << 5;
        gload_lds16(pB0 + ko, Ls + 8192 + wsl);
        gload_lds16(pB1 + ko, Ls + 12288 + wsl);
    };

    f32x4 acc[8][4] = {};

    constexpr int NK = FF_ / 32;  // 128
    STAGE_A(0); STAGE_B(0); STAGE_A(1); STAGE_B(1); STAGE_A(2); STAGE_B(2);
    for (int t = 0; t < NK; ++t) {
        if (t + 2 < NK)      { WAITV(8); }
        else if (t + 1 < NK) { WAITV(4); }
        else                 { WAITV(0); }
        BAR();
        const u16* Ls = lds + ((t & 3) << 14);
        bf16x8 af[8], bfv[4];
#pragma unroll
        for (int f = 0; f < 4; f++) af[f] = *(const bf16x8*)(Ls + aoff + f * 512);
#pragma unroll
        for (int n = 0; n < 4; n++) bfv[n] = *(const bf16x8*)(Ls + boff + n * 512);
        if (t + 3 < NK) STAGE_A(t + 3);
        WAITL0();
        __builtin_amdgcn_s_setprio(1);
#pragma unroll
        for (int f = 0; f < 4; f++)
#pragma unroll
            for (int n = 0; n < 4; n++)
                acc[f][n] = __builtin_amdgcn_mfma_f32_16x16x32_bf16(af[f], bfv[n], acc[f][n], 0, 0, 0);
        __builtin_amdgcn_s_setprio(0);
        BAR();
#pragma unroll
        for (int f = 4; f < 8; f++) af[f] = *(const bf16x8*)(Ls + aoff + f * 512);
        if (t + 3 < NK) STAGE_B(t + 3);
        WAITL0();
        __builtin_amdgcn_s_setprio(1);
#pragma unroll
        for (int f = 4; f < 8; f++)
#pragma unroll
            for (int n = 0; n < 4; n++)
                acc[f][n] = __builtin_amdgcn_mfma_f32_16x16x32_bf16(af[f], bfv[n], acc[f][n], 0, 0, 0);
        __builtin_amdgcn_s_setprio(0);
    }

#pragma unroll
    for (int f = 0; f < 8; f++) {
        int row = wm * 128 + f * 16 + ((l >> 4) << 2);
#pragma unroll
        for (int rr = 0; rr < 4; rr++) {
            int slot = c0 + row + rr;
            if (slot < cnt) {
                int s = slot_token[z * C_ + slot];
                float sc = maxp[b * S_ + s];
                float* orow = out + ((size_t)b * S_ + s) * D_ + n0 + wn * 64 + (l & 15);
#pragma unroll
                for (int n = 0; n < 4; n++)
                    orow[n * 16] = sc * acc[f][n][rr];
            }
        }
    }
}

// ============ dropped tokens keep hidden (rare; usually no-op) ============
__global__ __launch_bounds__(256) void combine_dropped(const float* __restrict__ hidden,
                                                       const int* __restrict__ pos,
                                                       const float* __restrict__ maxp,
                                                       float* __restrict__ out) {
    int t = blockIdx.x;
    if (pos[t] < C_) return;
    float sc = maxp[t];
    const float* src = hidden + (size_t)t * D_;
    float* dst = out + (size_t)t * D_;
    for (int d = threadIdx.x; d < D_; d += 256) dst[d] = sc * src[d];
}

extern "C" void kernel_launch(void* const* d_in, const int* in_sizes, int n_in,
                              void* d_out, int out_size, void* d_ws, size_t ws_size,
                              hipStream_t stream) {
    const float* hidden = (const float*)d_in[0];
    const float* gate_w = (const float*)d_in[1];
    const float* w1     = (const float*)d_in[2];
    const float* w2     = (const float*)d_in[3];
    const float* w3     = (const float*)d_in[4];

    float* out        = (float*)d_out;
    float* logits_out = out + (size_t)B_ * S_ * D_;

    char* ws = (char*)d_ws;
    u16* xg        = (u16*)ws;            ws += (size_t)B_ * E_ * C_ * D_ * 2;   // 32 MB
    u16* w1t       = (u16*)ws;            ws += (size_t)E_ * D_ * FF_ * 2;
    u16* w3t       = (u16*)ws;            ws += (size_t)E_ * D_ * FF_ * 2;
    u16* w2t       = (u16*)ws;            ws += (size_t)E_ * D_ * FF_ * 2;
    u16* hbuf      = (u16*)ws;            ws += (size_t)B_ * E_ * C_ * FF_ * 2;
    int*   sel        = (int*)ws;         ws += (size_t)B_ * S_ * 4;
    int*   pos        = (int*)ws;         ws += (size_t)B_ * S_ * 4;
    float* maxp       = (float*)ws;       ws += (size_t)B_ * S_ * 4;
    int*   slot_token = (int*)ws;         ws += (size_t)B_ * E_ * C_ * 4;
    int*   counts     = (int*)ws;         ws += (size_t)B_ * E_ * 4;

    (void)hipFuncSetAttribute((const void*)gemm1_kernel,
                              hipFuncAttributeMaxDynamicSharedMemorySize, 131072);
    (void)hipFuncSetAttribute((const void*)gemm2_kernel,
                              hipFuncAttributeMaxDynamicSharedMemorySize, 131072);

    router_kernel<<<B_ * S_ / 4, 256, 0, stream>>>(hidden, gate_w, logits_out, sel, maxp);
    scan_kernel<<<B_, 1024, 0, stream>>>(sel, pos, slot_token, counts);
    gather_kernel<<<B_ * E_ * 256, 256, 0, stream>>>(hidden, slot_token, counts, xg);

    transpose_cvt<<<dim3(FF_ / 64, D_ / 64, E_), 256, 0, stream>>>(w1, w1t, D_, FF_);
    transpose_cvt<<<dim3(FF_ / 64, D_ / 64, E_), 256, 0, stream>>>(w3, w3t, D_, FF_);
    transpose_cvt<<<dim3(D_ / 64, FF_ / 64, E_), 256, 0, stream>>>(w2, w2t, FF_, D_);

    gemm1_kernel<<<2048, 512, 131072, stream>>>(xg, w1t, w3t, counts, hbuf);
    gemm2_kernel<<<dim3(4, 4, 16), 512, 131072, stream>>>(hbuf, w2t, slot_token, counts, maxp, out);
    combine_dropped<<<B_ * S_, 256, 0, stream>>>(hidden, pos, maxp, out);
}

// Round 14
// 468.349 us; speedup vs baseline: 1.4574x; 1.1000x over previous
//
#include <hip/hip_runtime.h>
#include <hip/hip_bf16.h>
#include <stdint.h>

#define B_  2
#define S_  4096
#define D_  1024
#define FF_ 4096
#define E_  8
#define C_  1024

typedef unsigned short u16;
typedef unsigned int   u32;
typedef float f32x4  __attribute__((ext_vector_type(4)));
typedef short bf16x8 __attribute__((ext_vector_type(8)));
typedef u16   u16x8  __attribute__((ext_vector_type(8)));

static __device__ __forceinline__ u16 f2bf(float f) {
    union { float f; u32 u; } v; v.f = f;
    u32 u = v.u;
    u32 r = (u + 0x7FFFu + ((u >> 16) & 1u)) >> 16;  // RNE; inputs are finite
    return (u16)r;
}

static __device__ __forceinline__ void gload_lds16(const u16* g, u16* l) {
    __builtin_amdgcn_global_load_lds(
        (const __attribute__((address_space(1))) u32*)g,
        (__attribute__((address_space(3))) u32*)l, 16, 0, 0);
}

#define BAR()    asm volatile("s_barrier" ::: "memory")
#define WAITV(n) asm volatile("s_waitcnt vmcnt(" #n ")" ::: "memory")
#define WAITL0() do { asm volatile("s_waitcnt lgkmcnt(0)" ::: "memory"); \
                      __builtin_amdgcn_sched_barrier(0); } while (0)

// ============ transpose + convert: [K][N] fp32 -> [N][K] bf16, per expert ============
__global__ __launch_bounds__(256) void transpose_cvt(const float* __restrict__ src,
                                                     u16* __restrict__ dst, int K, int N) {
    __shared__ u16 t[64 * 64];
    size_t mat = (size_t)blockIdx.z * K * N;
    int n0 = blockIdx.x * 64, k0 = blockIdx.y * 64;
    int l = threadIdx.x & 63, w = threadIdx.x >> 6;
#pragma unroll
    for (int p = 0; p < 2; ++p) {
        int k = p * 32 + w * 8 + ((l >> 4) << 1);     // even k
        int n = (l & 15) * 4;
        float4 v0 = *(const float4*)&src[mat + (size_t)(k0 + k) * N + n0 + n];
        float4 v1 = *(const float4*)&src[mat + (size_t)(k0 + k + 1) * N + n0 + n];
        float a0[4] = {v0.x, v0.y, v0.z, v0.w};
        float a1[4] = {v1.x, v1.y, v1.z, v1.w};
#pragma unroll
        for (int j = 0; j < 4; ++j) {
            int nn = n + j;
            u32 pk = (u32)f2bf(a0[j]) | ((u32)f2bf(a1[j]) << 16);
            int slot = (k >> 3) ^ ((nn & 7) ^ ((nn >> 3) & 7));
            *(u32*)((char*)t + nn * 128 + slot * 16 + (k & 7) * 2) = pk;
        }
    }
    __syncthreads();
#pragma unroll
    for (int p = 0; p < 2; ++p) {
        int n = p * 32 + (threadIdx.x >> 3);
        int k8 = threadIdx.x & 7;
        int slot = k8 ^ ((n & 7) ^ ((n >> 3) & 7));
        u16x8 v = *(u16x8*)((char*)t + n * 128 + slot * 16);
        *(u16x8*)&dst[mat + (size_t)(n0 + n) * K + k0 + k8 * 8] = v;
    }
}

// ============ router: logits (fp64 accum), argmax, max softmax prob; fused bf16 cvt ============
__global__ __launch_bounds__(256) void router_kernel(const float* __restrict__ hidden,
                                                     const float* __restrict__ gate_w,
                                                     float* __restrict__ logits_out,
                                                     int* __restrict__ sel,
                                                     float* __restrict__ maxp,
                                                     u16* __restrict__ xbf) {
    __shared__ float gw[D_ * E_];   // 32 KB
    for (int i = threadIdx.x; i < D_ * E_ / 4; i += 256)
        ((float4*)gw)[i] = ((const float4*)gate_w)[i];
    __syncthreads();

    int wave = threadIdx.x >> 6, lane = threadIdx.x & 63;
    int tok = blockIdx.x * 4 + wave;              // [0, B*S)
    const float* hrow = hidden + (size_t)tok * D_;
    u16* xrow = xbf + (size_t)tok * D_;

    double acc[8] = {0, 0, 0, 0, 0, 0, 0, 0};
#pragma unroll 4
    for (int i = 0; i < D_ / 64; i++) {
        int d = i * 64 + lane;
        float h = hrow[d];
        xrow[d] = f2bf(h);
        const float4* g4 = (const float4*)(gw + d * 8);
        float4 g0 = g4[0], g1 = g4[1];
        acc[0] += (double)h * g0.x; acc[1] += (double)h * g0.y;
        acc[2] += (double)h * g0.z; acc[3] += (double)h * g0.w;
        acc[4] += (double)h * g1.x; acc[5] += (double)h * g1.y;
        acc[6] += (double)h * g1.z; acc[7] += (double)h * g1.w;
    }
#pragma unroll
    for (int off = 32; off > 0; off >>= 1)
#pragma unroll
        for (int e = 0; e < 8; e++)
            acc[e] += __shfl_xor(acc[e], off);

    float l[8];
#pragma unroll
    for (int e = 0; e < 8; e++) l[e] = (float)acc[e];
    if (lane < 8) logits_out[(size_t)tok * 8 + lane] = l[lane];

    int am = 0; float mx = l[0];
#pragma unroll
    for (int e = 1; e < 8; e++) if (l[e] > mx) { mx = l[e]; am = e; }
    float sum = 0.f;
#pragma unroll
    for (int e = 0; e < 8; e++) sum += expf(l[e] - mx);
    if (lane == 0) { sel[tok] = am; maxp[tok] = 1.0f / sum; }
}

// ============ routing scan: hierarchical (histogram -> prefix -> assign), 1 block/batch ============
__global__ __launch_bounds__(1024) void scan_kernel(const int* __restrict__ sel,
                                                    int* __restrict__ pos,
                                                    int* __restrict__ slot_token,
                                                    int* __restrict__ counts) {
    __shared__ int hist[16][8];
    __shared__ int base[16][8];
    int b = blockIdx.x;
    int tid = threadIdx.x, wv = tid >> 6, l = tid & 63;
    unsigned long long below = (l == 0) ? 0ull : ((~0ull) >> (64 - l));
    const int* sb = sel + b * S_;

    int eloc[4];
    int cnt[8] = {0, 0, 0, 0, 0, 0, 0, 0};
#pragma unroll
    for (int c = 0; c < 4; c++) {
        int s = wv * 256 + c * 64 + l;
        int e = sb[s];
        eloc[c] = e;
#pragma unroll
        for (int ex = 0; ex < 8; ex++)
            cnt[ex] += (int)__popcll(__ballot(e == ex));
    }
    if (l == 0)
#pragma unroll
        for (int ex = 0; ex < 8; ex++) hist[wv][ex] = cnt[ex];
    __syncthreads();
    if (tid < 128) {
        int ex = tid & 7, v = tid >> 3;
        int s = 0;
        for (int w2 = 0; w2 < v; w2++) s += hist[w2][ex];
        base[v][ex] = s;
        if (v == 15) {
            int tot = s + hist[15][ex];
            counts[b * 8 + ex] = tot < C_ ? tot : C_;
        }
    }
    __syncthreads();
    int carry[8];
#pragma unroll
    for (int ex = 0; ex < 8; ex++) carry[ex] = base[wv][ex];
#pragma unroll
    for (int c = 0; c < 4; c++) {
        int s = wv * 256 + c * 64 + l;
        int e = eloc[c];
        int p = 0;
#pragma unroll
        for (int ex = 0; ex < 8; ex++) {
            unsigned long long m = __ballot(e == ex);
            if (e == ex) p = carry[ex] + (int)__popcll(m & below);
            carry[ex] += (int)__popcll(m);
        }
        pos[b * S_ + s] = p;
        if (p < C_) slot_token[(b * E_ + e) * C_ + p] = s;
    }
}

// ============ GEMM1: h = silu(x@w1) * (x@w3) — best measured variant (R5 bench: 220 us) ============
// tile 256(M slots, slot_token-indexed) x 128(N per panel). K-step=32, 4-slot LDS rotation,
// prefetch depth 3, 8 waves (2M x 4N). Sub-phases: per step, 2x {reads || stage-half ->
// lgkm(0) -> setprio(1) 16 MFMA} with one mid-step barrier. vmcnt never 0 mid-loop.
__global__ __launch_bounds__(512, 2) void gemm1_kernel(const u16* __restrict__ x,
                                                       const u16* __restrict__ w1t,
                                                       const u16* __restrict__ w3t,
                                                       const int* __restrict__ slot_token,
                                                       const int* __restrict__ counts,
                                                       u16* __restrict__ hbuf) {
    extern __shared__ u16 lds[];   // 4 * 16384 u16 = 128 KB
    // bijective XCD chunk swizzle (nwg = 2048, q = 256)
    int phys = blockIdx.x + 32 * (blockIdx.y + 4 * blockIdx.z);
    int virt = (phys & 7) * 256 + (phys >> 3);
    int bx = virt & 31, by = (virt >> 5) & 3, bz = virt >> 7;

    int z = bz;
    int cnt = counts[z];
    int c0 = by * 256;
    if (c0 >= cnt) return;
    int n0 = bx * 128;
    int b = z >> 3, e = z & 7;

    int tid = threadIdx.x, w = tid >> 6, l = tid & 63;
    int wm = w >> 2, wn = w & 3;

    // staging: thread writes phys chunk (tid&3) of row (tid>>2); source k-chunk inverse-swizzled
    int arow0 = tid >> 2, arow1 = arow0 + 128;
    int lk = ((tid & 3) ^ ((tid >> 3) & 3)) * 8;   // (row>>1)&3 identical for row and row+128
    int as0 = c0 + arow0, as1 = c0 + arow1;
    int tok0 = slot_token[z * C_ + (as0 < cnt ? as0 : 0)];
    int tok1 = slot_token[z * C_ + (as1 < cnt ? as1 : 0)];
    const u16* pA0 = x + ((size_t)(b * S_ + tok0)) * D_ + lk;
    const u16* pA1 = x + ((size_t)(b * S_ + tok1)) * D_ + lk;
    const u16* pB1 = w1t + ((size_t)e * FF_ + n0 + arow0) * D_ + lk;
    const u16* pB3 = w3t + ((size_t)e * FF_ + n0 + arow0) * D_ + lk;
    u32 wA0 = (u32)tid * 8, wA1 = (u32)tid * 8 + 4096;
    u32 wB1 = 8192 + (u32)tid * 8, wB3 = 12288 + (u32)tid * 8;

    u32 ck  = (u32)(((l >> 4) ^ ((l >> 1) & 3)) * 8);
    u32 aoff  = (u32)(wm * 128 + (l & 15)) * 32 + ck;                 // + f*512
    u32 b1off = 8192  + (u32)(wn * 32 + (l & 15)) * 32 + ck;          // + n*512
    u32 b3off = 12288 + (u32)(wn * 32 + (l & 15)) * 32 + ck;

    auto STAGE_A = [&](int t) {
        u16* Ls = lds + ((t & 3) << 14);
        int ko = t << 5;
        gload_lds16(pA0 + ko, Ls + wA0);
        gload_lds16(pA1 + ko, Ls + wA1);
    };
    auto STAGE_B = [&](int t) {
        u16* Ls = lds + ((t & 3) << 14);
        int ko = t << 5;
        gload_lds16(pB1 + ko, Ls + wB1);
        gload_lds16(pB3 + ko, Ls + wB3);
    };

    f32x4 acc1[8][2] = {};
    f32x4 acc3[8][2] = {};

    constexpr int NK = D_ / 32;  // 32
    STAGE_A(0); STAGE_B(0); STAGE_A(1); STAGE_B(1); STAGE_A(2); STAGE_B(2);
    for (int t = 0; t < NK; ++t) {
        if (t + 2 < NK)      { WAITV(8); }
        else if (t + 1 < NK) { WAITV(4); }
        else                 { WAITV(0); }
        BAR();
        const u16* Ls = lds + ((t & 3) << 14);
        // ---- sub-phase 0: af0..3 + all B frags; stage A-half of t+3 ----
        bf16x8 af[8], b1f[2], b3f[2];
#pragma unroll
        for (int f = 0; f < 4; f++) af[f] = *(const bf16x8*)(Ls + aoff + f * 512);
#pragma unroll
        for (int n = 0; n < 2; n++) {
            b1f[n] = *(const bf16x8*)(Ls + b1off + n * 512);
            b3f[n] = *(const bf16x8*)(Ls + b3off + n * 512);
        }
        if (t + 3 < NK) STAGE_A(t + 3);
        WAITL0();
        __builtin_amdgcn_s_setprio(1);
#pragma unroll
        for (int f = 0; f < 4; f++)
#pragma unroll
            for (int n = 0; n < 2; n++) {
                acc1[f][n] = __builtin_amdgcn_mfma_f32_16x16x32_bf16(af[f], b1f[n], acc1[f][n], 0, 0, 0);
                acc3[f][n] = __builtin_amdgcn_mfma_f32_16x16x32_bf16(af[f], b3f[n], acc3[f][n], 0, 0, 0);
            }
        __builtin_amdgcn_s_setprio(0);
        BAR();
        // ---- sub-phase 1: af4..7; stage B-half of t+3 ----
#pragma unroll
        for (int f = 4; f < 8; f++) af[f] = *(const bf16x8*)(Ls + aoff + f * 512);
        if (t + 3 < NK) STAGE_B(t + 3);
        WAITL0();
        __builtin_amdgcn_s_setprio(1);
#pragma unroll
        for (int f = 4; f < 8; f++)
#pragma unroll
            for (int n = 0; n < 2; n++) {
                acc1[f][n] = __builtin_amdgcn_mfma_f32_16x16x32_bf16(af[f], b1f[n], acc1[f][n], 0, 0, 0);
                acc3[f][n] = __builtin_amdgcn_mfma_f32_16x16x32_bf16(af[f], b3f[n], acc3[f][n], 0, 0, 0);
            }
        __builtin_amdgcn_s_setprio(0);
    }

#pragma unroll
    for (int f = 0; f < 8; f++) {
        int row = wm * 128 + f * 16 + ((l >> 4) << 2);
#pragma unroll
        for (int rr = 0; rr < 4; rr++) {
            int slot = c0 + row + rr;
            if (slot < cnt) {
                size_t base = ((size_t)z * C_ + slot) * FF_ + n0 + wn * 32 + (l & 15);
#pragma unroll
                for (int n = 0; n < 2; n++) {
                    float g = acc1[f][n][rr], uu = acc3[f][n][rr];
                    float h = (g / (1.f + __expf(-g))) * uu;
                    hbuf[base + n * 16] = f2bf(h);
                }
            }
        }
    }
}

// ============ GEMM2: out[token] = maxp * (h @ w2), scatter epilogue ============
// tile 256(M) x 256(N). K-step=32, 4-slot rotation, depth 3, 8 waves (2M x 4N),
// 2-sub-phase schedule.
__global__ __launch_bounds__(512, 2) void gemm2_kernel(const u16* __restrict__ hbuf,
                                                       const u16* __restrict__ w2t,
                                                       const int* __restrict__ slot_token,
                                                       const int* __restrict__ counts,
                                                       const float* __restrict__ maxp,
                                                       float* __restrict__ out) {
    extern __shared__ u16 lds[];   // 128 KB
    // bijective XCD chunk swizzle (nwg = 256, q = 32)
    int phys = blockIdx.x + 4 * (blockIdx.y + 4 * blockIdx.z);
    int virt = (phys & 7) * 32 + (phys >> 3);
    int bx = virt & 3, by = (virt >> 2) & 3, bz = virt >> 4;

    int z = bz;
    int cnt = counts[z];
    int c0 = by * 256;
    if (c0 >= cnt) return;
    int n0 = bx * 256;
    int b = z >> 3, e = z & 7;

    int tid = threadIdx.x, w = tid >> 6, l = tid & 63;
    int wm = w >> 2, wn = w & 3;

    int arow0 = tid >> 2;
    int lk = ((tid & 3) ^ ((tid >> 3) & 3)) * 8;
    const u16* pA0 = hbuf + ((size_t)z * C_ + c0 + arow0) * FF_ + lk;
    const u16* pA1 = pA0 + (size_t)128 * FF_;
    const u16* pB0 = w2t + ((size_t)e * D_ + n0 + arow0) * FF_ + lk;
    const u16* pB1 = pB0 + (size_t)128 * FF_;
    u32 wsl = (u32)tid * 8;

    u32 ck  = (u32)(((l >> 4) ^ ((l >> 1) & 3)) * 8);
    u32 aoff = (u32)(wm * 128 + (l & 15)) * 32 + ck;                 // + f*512
    u32 boff = 8192 + (u32)(wn * 64 + (l & 15)) * 32 + ck;           // + n*512

    auto STAGE_A = [&](int t) {
        u16* Ls = lds + ((t & 3) << 14);
        int ko = t << 5;
        gload_lds16(pA0 + ko, Ls + wsl);
        gload_lds16(pA1 + ko, Ls + 4096 + wsl);
    };
    auto STAGE_B = [&](int t) {
        u16* Ls = lds + ((t & 3) << 14);
        int ko = t << 5;
        gload_lds16(pB0 + ko, Ls + 8192 + wsl);
        gload_lds16(pB1 + ko, Ls + 12288 + wsl);
    };

    f32x4 acc[8][4] = {};

    constexpr int NK = FF_ / 32;  // 128
    STAGE_A(0); STAGE_B(0); STAGE_A(1); STAGE_B(1); STAGE_A(2); STAGE_B(2);
    for (int t = 0; t < NK; ++t) {
        if (t + 2 < NK)      { WAITV(8); }
        else if (t + 1 < NK) { WAITV(4); }
        else                 { WAITV(0); }
        BAR();
        const u16* Ls = lds + ((t & 3) << 14);
        bf16x8 af[8], bfv[4];
#pragma unroll
        for (int f = 0; f < 4; f++) af[f] = *(const bf16x8*)(Ls + aoff + f * 512);
#pragma unroll
        for (int n = 0; n < 4; n++) bfv[n] = *(const bf16x8*)(Ls + boff + n * 512);
        if (t + 3 < NK) STAGE_A(t + 3);
        WAITL0();
        __builtin_amdgcn_s_setprio(1);
#pragma unroll
        for (int f = 0; f < 4; f++)
#pragma unroll
            for (int n = 0; n < 4; n++)
                acc[f][n] = __builtin_amdgcn_mfma_f32_16x16x32_bf16(af[f], bfv[n], acc[f][n], 0, 0, 0);
        __builtin_amdgcn_s_setprio(0);
        BAR();
#pragma unroll
        for (int f = 4; f < 8; f++) af[f] = *(const bf16x8*)(Ls + aoff + f * 512);
        if (t + 3 < NK) STAGE_B(t + 3);
        WAITL0();
        __builtin_amdgcn_s_setprio(1);
#pragma unroll
        for (int f = 4; f < 8; f++)
#pragma unroll
            for (int n = 0; n < 4; n++)
                acc[f][n] = __builtin_amdgcn_mfma_f32_16x16x32_bf16(af[f], bfv[n], acc[f][n], 0, 0, 0);
        __builtin_amdgcn_s_setprio(0);
    }

#pragma unroll
    for (int f = 0; f < 8; f++) {
        int row = wm * 128 + f * 16 + ((l >> 4) << 2);
#pragma unroll
        for (int rr = 0; rr < 4; rr++) {
            int slot = c0 + row + rr;
            if (slot < cnt) {
                int s = slot_token[z * C_ + slot];
                float sc = maxp[b * S_ + s];
                float* orow = out + ((size_t)b * S_ + s) * D_ + n0 + wn * 64 + (l & 15);
#pragma unroll
                for (int n = 0; n < 4; n++)
                    orow[n * 16] = sc * acc[f][n][rr];
            }
        }
    }
}

// ============ dropped tokens keep hidden (rare; usually no-op) ============
__global__ __launch_bounds__(256) void combine_dropped(const float* __restrict__ hidden,
                                                       const int* __restrict__ pos,
                                                       const float* __restrict__ maxp,
                                                       float* __restrict__ out) {
    int t = blockIdx.x;
    if (pos[t] < C_) return;
    float sc = maxp[t];
    const float* src = hidden + (size_t)t * D_;
    float* dst = out + (size_t)t * D_;
    for (int d = threadIdx.x; d < D_; d += 256) dst[d] = sc * src[d];
}

extern "C" void kernel_launch(void* const* d_in, const int* in_sizes, int n_in,
                              void* d_out, int out_size, void* d_ws, size_t ws_size,
                              hipStream_t stream) {
    const float* hidden = (const float*)d_in[0];
    const float* gate_w = (const float*)d_in[1];
    const float* w1     = (const float*)d_in[2];
    const float* w2     = (const float*)d_in[3];
    const float* w3     = (const float*)d_in[4];

    float* out        = (float*)d_out;
    float* logits_out = out + (size_t)B_ * S_ * D_;

    char* ws = (char*)d_ws;
    u16* hidden_bf = (u16*)ws;            ws += (size_t)B_ * S_ * D_ * 2;
    u16* w1t       = (u16*)ws;            ws += (size_t)E_ * D_ * FF_ * 2;
    u16* w3t       = (u16*)ws;            ws += (size_t)E_ * D_ * FF_ * 2;
    u16* w2t       = (u16*)ws;            ws += (size_t)E_ * D_ * FF_ * 2;
    u16* hbuf      = (u16*)ws;            ws += (size_t)B_ * E_ * C_ * FF_ * 2;
    int*   sel        = (int*)ws;         ws += (size_t)B_ * S_ * 4;
    int*   pos        = (int*)ws;         ws += (size_t)B_ * S_ * 4;
    float* maxp       = (float*)ws;       ws += (size_t)B_ * S_ * 4;
    int*   slot_token = (int*)ws;         ws += (size_t)B_ * E_ * C_ * 4;
    int*   counts     = (int*)ws;         ws += (size_t)B_ * E_ * 4;

    (void)hipFuncSetAttribute((const void*)gemm1_kernel,
                              hipFuncAttributeMaxDynamicSharedMemorySize, 131072);
    (void)hipFuncSetAttribute((const void*)gemm2_kernel,
                              hipFuncAttributeMaxDynamicSharedMemorySize, 131072);

    router_kernel<<<B_ * S_ / 4, 256, 0, stream>>>(hidden, gate_w, logits_out, sel, maxp, hidden_bf);
    scan_kernel<<<B_, 1024, 0, stream>>>(sel, pos, slot_token, counts);

    transpose_cvt<<<dim3(FF_ / 64, D_ / 64, E_), 256, 0, stream>>>(w1, w1t, D_, FF_);
    transpose_cvt<<<dim3(FF_ / 64, D_ / 64, E_), 256, 0, stream>>>(w3, w3t, D_, FF_);
    transpose_cvt<<<dim3(D_ / 64, FF_ / 64, E_), 256, 0, stream>>>(w2, w2t, FF_, D_);

    gemm1_kernel<<<dim3(32, 4, 16), 512, 131072, stream>>>(hidden_bf, w1t, w3t, slot_token, counts, hbuf);
    gemm2_kernel<<<dim3(4, 4, 16), 512, 131072, stream>>>(hbuf, w2t, slot_token, counts, maxp, out);
    combine_dropped<<<B_ * S_, 256, 0, stream>>>(hidden, pos, maxp, out);
}